// Round 1
// baseline (288.997 us; speedup 1.0000x reference)
//
#include <hip/hip_runtime.h>

#define Bd 16
#define Cd 512
#define Hd 64
#define Wd 64
#define HWd (Hd * Wd)
#define NCLS 5
#define BETA 2.0f
#define EPS2 (0.001f * 0.001f)

// channel-chunking: each block reduces CH channels for 1024 pixels
constexpr int CH = 32;
constexpr int NCCHUNK = Cd / CH;      // 16
constexpr int PIX_PER_BLOCK = 1024;   // 256 threads * 4 pixels (float4)

// Kernel 1: per-pixel channel-MSE partial sums -> per-(batch,class) segment sums.
// grid = (HW/1024, B, NCCHUNK), block = 256
__global__ __launch_bounds__(256) void seg_partial_kernel(
    const float* __restrict__ rec, const float* __restrict__ aln,
    const int* __restrict__ mask,
    float* __restrict__ segsum, float* __restrict__ segcnt)
{
    __shared__ float binS[NCLS];
    __shared__ float binC[NCLS];
    const int tid = threadIdx.x;
    if (tid < NCLS) { binS[tid] = 0.0f; binC[tid] = 0.0f; }
    __syncthreads();

    const int b   = blockIdx.y;
    const int hw0 = blockIdx.x * PIX_PER_BLOCK + tid * 4;
    const int c0  = blockIdx.z * CH;

    const size_t base = (size_t)(b * Cd + c0) * HWd + hw0;
    const float4* __restrict__ rv = (const float4*)(rec + base);
    const float4* __restrict__ av = (const float4*)(aln + base);

    float4 acc = make_float4(0.f, 0.f, 0.f, 0.f);
#pragma unroll 8
    for (int c = 0; c < CH; ++c) {
        float4 r = rv[c * (HWd / 4)];
        float4 a = av[c * (HWd / 4)];
        float dx = r.x - a.x, dy = r.y - a.y, dz = r.z - a.z, dw = r.w - a.w;
        acc.x += dx * dx;
        acc.y += dy * dy;
        acc.z += dz * dz;
        acc.w += dw * dw;
    }

    const float scale = 1.0f / (float)Cd;   // channel mean
    const int4 m = *(const int4*)(mask + b * HWd + hw0);
    atomicAdd(&binS[m.x], acc.x * scale);
    atomicAdd(&binS[m.y], acc.y * scale);
    atomicAdd(&binS[m.z], acc.z * scale);
    atomicAdd(&binS[m.w], acc.w * scale);
    if (blockIdx.z == 0) {
        atomicAdd(&binC[m.x], 1.0f);
        atomicAdd(&binC[m.y], 1.0f);
        atomicAdd(&binC[m.z], 1.0f);
        atomicAdd(&binC[m.w], 1.0f);
    }
    __syncthreads();
    if (tid < NCLS) {
        atomicAdd(&segsum[b * NCLS + tid], binS[tid]);
        if (blockIdx.z == 0) atomicAdd(&segcnt[b * NCLS + tid], binC[tid]);
    }
}

// Kernel 2: 80 segments -> scalar. One block of 128 threads.
__global__ __launch_bounds__(128) void finalize_kernel(
    const float* __restrict__ segsum, const float* __restrict__ segcnt,
    float* __restrict__ out)
{
    __shared__ float sMax[128];
    __shared__ float sSum[128];
    const int t = threadIdx.x;

    float s = 0.0f, cnt = 0.0f;
    if (t < Bd * NCLS) { s = segsum[t]; cnt = segcnt[t]; }
    const float avg = s / fmaxf(cnt, 1.0f);   // empty segments -> 0 (never raises max; sums=0 so no term)

    sMax[t] = avg;
    __syncthreads();
#pragma unroll
    for (int off = 64; off > 0; off >>= 1) {
        if (t < off) sMax[t] = fmaxf(sMax[t], sMax[t + off]);
        __syncthreads();
    }
    const float wmax = sMax[0];

    float w = (wmax > 0.0f) ? (avg / (wmax + EPS2)) : (avg + EPS2);
    w = fminf(fmaxf(w, 0.0f), 1.0f);

    sSum[t] = s * (w * BETA + 1.0f);
    __syncthreads();
#pragma unroll
    for (int off = 64; off > 0; off >>= 1) {
        if (t < off) sSum[t] += sSum[t + off];
        __syncthreads();
    }
    if (t == 0) out[0] = sSum[0] / (float)(Bd * HWd);
}

extern "C" void kernel_launch(void* const* d_in, const int* in_sizes, int n_in,
                              void* d_out, int out_size, void* d_ws, size_t ws_size,
                              hipStream_t stream) {
    const float* rec  = (const float*)d_in[0];
    const float* aln  = (const float*)d_in[1];
    const int*   mask = (const int*)d_in[2];
    float* out = (float*)d_out;

    float* segsum = (float*)d_ws;
    float* segcnt = segsum + Bd * NCLS;

    // zero the 2*80 accumulators (ws is re-poisoned to 0xAA before every launch)
    hipMemsetAsync(d_ws, 0, 2 * Bd * NCLS * sizeof(float), stream);

    dim3 grid(HWd / PIX_PER_BLOCK, Bd, NCCHUNK);   // (4, 16, 16) = 1024 blocks
    seg_partial_kernel<<<grid, 256, 0, stream>>>(rec, aln, mask, segsum, segcnt);
    finalize_kernel<<<1, 128, 0, stream>>>(segsum, segcnt, out);
}

// Round 2
// 285.875 us; speedup vs baseline: 1.0109x; 1.0109x over previous
//
#include <hip/hip_runtime.h>

#define Bd 16
#define Cd 512
#define Hd 64
#define Wd 64
#define HWd (Hd * Wd)
#define NCLS 5
#define BETA 2.0f
#define EPS2 (0.001f * 0.001f)

// channel-chunking: each block reduces CH channels for 1024 pixels.
// CH=16 -> grid 2048 blocks -> 8 blocks/CU, 32 waves/CU at VGPR<=64.
constexpr int CH = 16;
constexpr int NCCHUNK = Cd / CH;      // 32
constexpr int PIX_PER_BLOCK = 1024;   // 256 threads * 4 pixels (float4)

// Kernel 1: per-pixel channel-MSE partial sums -> per-(batch,class) segment sums.
// grid = (HW/1024, B, NCCHUNK), block = 256
__global__ __launch_bounds__(256, 8) void seg_partial_kernel(
    const float* __restrict__ rec, const float* __restrict__ aln,
    const int* __restrict__ mask,
    float* __restrict__ segsum, float* __restrict__ segcnt)
{
    __shared__ float binS[NCLS];
    __shared__ float binC[NCLS];
    const int tid = threadIdx.x;
    if (tid < NCLS) { binS[tid] = 0.0f; binC[tid] = 0.0f; }
    __syncthreads();

    const int b   = blockIdx.y;
    const int hw0 = blockIdx.x * PIX_PER_BLOCK + tid * 4;
    const int c0  = blockIdx.z * CH;

    const size_t base = (size_t)(b * Cd + c0) * HWd + hw0;
    const float4* __restrict__ rv = (const float4*)(rec + base);
    const float4* __restrict__ av = (const float4*)(aln + base);
    constexpr int CSTRIDE = HWd / 4;   // float4 stride between channels

    // independent mask load (L2-resident, shared by all c-chunks)
    const int4 m = *(const int4*)(mask + b * HWd + hw0);

    float4 acc = make_float4(0.f, 0.f, 0.f, 0.f);
    // manual 4-channel unroll: 8 dwordx4 loads issued before any use,
    // so the wave keeps 8 KB outstanding instead of 2 KB + vmcnt(0) drain.
#pragma unroll
    for (int cb = 0; cb < CH; cb += 4) {
        const float4* r4 = rv + (size_t)cb * CSTRIDE;
        const float4* a4 = av + (size_t)cb * CSTRIDE;
        float4 r0 = r4[0 * CSTRIDE];
        float4 r1 = r4[1 * CSTRIDE];
        float4 r2 = r4[2 * CSTRIDE];
        float4 r3 = r4[3 * CSTRIDE];
        float4 a0 = a4[0 * CSTRIDE];
        float4 a1 = a4[1 * CSTRIDE];
        float4 a2 = a4[2 * CSTRIDE];
        float4 a3 = a4[3 * CSTRIDE];

        float d;
        d = r0.x - a0.x; acc.x += d * d;
        d = r0.y - a0.y; acc.y += d * d;
        d = r0.z - a0.z; acc.z += d * d;
        d = r0.w - a0.w; acc.w += d * d;
        d = r1.x - a1.x; acc.x += d * d;
        d = r1.y - a1.y; acc.y += d * d;
        d = r1.z - a1.z; acc.z += d * d;
        d = r1.w - a1.w; acc.w += d * d;
        d = r2.x - a2.x; acc.x += d * d;
        d = r2.y - a2.y; acc.y += d * d;
        d = r2.z - a2.z; acc.z += d * d;
        d = r2.w - a2.w; acc.w += d * d;
        d = r3.x - a3.x; acc.x += d * d;
        d = r3.y - a3.y; acc.y += d * d;
        d = r3.z - a3.z; acc.z += d * d;
        d = r3.w - a3.w; acc.w += d * d;
    }

    const float scale = 1.0f / (float)Cd;   // channel mean
    atomicAdd(&binS[m.x], acc.x * scale);
    atomicAdd(&binS[m.y], acc.y * scale);
    atomicAdd(&binS[m.z], acc.z * scale);
    atomicAdd(&binS[m.w], acc.w * scale);
    if (blockIdx.z == 0) {
        atomicAdd(&binC[m.x], 1.0f);
        atomicAdd(&binC[m.y], 1.0f);
        atomicAdd(&binC[m.z], 1.0f);
        atomicAdd(&binC[m.w], 1.0f);
    }
    __syncthreads();
    if (tid < NCLS) {
        atomicAdd(&segsum[b * NCLS + tid], binS[tid]);
        if (blockIdx.z == 0) atomicAdd(&segcnt[b * NCLS + tid], binC[tid]);
    }
}

// Kernel 2: 80 segments -> scalar. One block of 128 threads.
__global__ __launch_bounds__(128) void finalize_kernel(
    const float* __restrict__ segsum, const float* __restrict__ segcnt,
    float* __restrict__ out)
{
    __shared__ float sMax[128];
    __shared__ float sSum[128];
    const int t = threadIdx.x;

    float s = 0.0f, cnt = 0.0f;
    if (t < Bd * NCLS) { s = segsum[t]; cnt = segcnt[t]; }
    const float avg = s / fmaxf(cnt, 1.0f);   // empty segments -> 0 (contribute nothing)

    sMax[t] = avg;
    __syncthreads();
#pragma unroll
    for (int off = 64; off > 0; off >>= 1) {
        if (t < off) sMax[t] = fmaxf(sMax[t], sMax[t + off]);
        __syncthreads();
    }
    const float wmax = sMax[0];

    float w = (wmax > 0.0f) ? (avg / (wmax + EPS2)) : (avg + EPS2);
    w = fminf(fmaxf(w, 0.0f), 1.0f);

    sSum[t] = s * (w * BETA + 1.0f);
    __syncthreads();
#pragma unroll
    for (int off = 64; off > 0; off >>= 1) {
        if (t < off) sSum[t] += sSum[t + off];
        __syncthreads();
    }
    if (t == 0) out[0] = sSum[0] / (float)(Bd * HWd);
}

extern "C" void kernel_launch(void* const* d_in, const int* in_sizes, int n_in,
                              void* d_out, int out_size, void* d_ws, size_t ws_size,
                              hipStream_t stream) {
    const float* rec  = (const float*)d_in[0];
    const float* aln  = (const float*)d_in[1];
    const int*   mask = (const int*)d_in[2];
    float* out = (float*)d_out;

    float* segsum = (float*)d_ws;
    float* segcnt = segsum + Bd * NCLS;

    // zero the 2*80 accumulators (ws is re-poisoned to 0xAA before every launch)
    hipMemsetAsync(d_ws, 0, 2 * Bd * NCLS * sizeof(float), stream);

    dim3 grid(HWd / PIX_PER_BLOCK, Bd, NCCHUNK);   // (4, 16, 32) = 2048 blocks
    seg_partial_kernel<<<grid, 256, 0, stream>>>(rec, aln, mask, segsum, segcnt);
    finalize_kernel<<<1, 128, 0, stream>>>(segsum, segcnt, out);
}